// Round 16
// baseline (44.884 us; speedup 1.0000x reference)
//
#include <hip/hip_runtime.h>
#include <math.h>

// DTM layer: B=32, N=1024, D=2, M0=0.05, R=2
// out = sqrt( (A_strict(t*) + t*(wb - S_strict(t*)))/wb ), t* = weighted
// 5%-quantile of d2, wb = 0.05*sum_b(w).
// R14 = R12 (integer LDS histogram bracketing, 2 interpolative refines,
//             TWO-SIDED concave-envelope epilogue — second-order accurate)
//     + R13's 4-copy staggered histogram (stride 65 dwords): same-bucket
//       atomic serialization <=16-way (was <=64), copies bank-skewed.
// R13's one-sided epilogue FAILED (absmax 0.0625 > 0.054): first-order error
// (hi-t*)(S-wb)/wb too big at worst-case bracket width. The envelope
// (tangent-intersection; exact when <=1 point inside bracket) at the same
// width gave 0.0078 in R12 -> restored verbatim.

constexpr int      PER_LANE   = 16;        // 1024 / 64
constexpr float    M0_        = 0.05f;
constexpr unsigned BUCKET_OFF = 476u;      // (bits>>21)-476: bucket 0 at d2=2^-8
constexpr float    WSCALE     = 1048576.0f;            // 2^20
constexpr float    WINV       = 9.5367431640625e-07f;  // 2^-20
constexpr int      NCOPY_STR  = 65;        // copy stride (bank skew)

template<int CTRL, int RM>
__device__ __forceinline__ unsigned dpp_uadd(unsigned v) {
    unsigned m = (unsigned)__builtin_amdgcn_update_dpp(0, (int)v, CTRL, RM, 0xF, true);
    return v + m;
}
template<int CTRL, int RM>
__device__ __forceinline__ float dpp_fadd(float v) {
    int m = __builtin_amdgcn_update_dpp(0, __float_as_int(v), CTRL, RM, 0xF, true);
    return v + __int_as_float(m);
}
__device__ __forceinline__ float lane63f(float v) {
    return __uint_as_float((unsigned)__builtin_amdgcn_readlane(__float_as_int(v), 63));
}

// u32 inclusive prefix scan across 64 lanes
__device__ __forceinline__ unsigned wave_scan_u32(unsigned v) {
    v = dpp_uadd<0x111,0xF>(v);    // row_shr:1
    v = dpp_uadd<0x112,0xF>(v);    // row_shr:2
    v = dpp_uadd<0x114,0xF>(v);    // row_shr:4
    v = dpp_uadd<0x118,0xF>(v);    // row_shr:8
    v = dpp_uadd<0x142,0xA>(v);    // row_bcast:15
    v = dpp_uadd<0x143,0xC>(v);    // row_bcast:31
    return v;                      // lane63 = total
}
__device__ __forceinline__ float wave_sum1(float v) {
    v = dpp_fadd<0x111,0xF>(v); v = dpp_fadd<0x112,0xF>(v);
    v = dpp_fadd<0x114,0xF>(v); v = dpp_fadd<0x118,0xF>(v);
    v = dpp_fadd<0x142,0xA>(v); v = dpp_fadd<0x143,0xC>(v);
    return lane63f(v);
}
// four interleaved float sums (latency overlap)
__device__ __forceinline__ void wave_sum4_u(float& a, float& b, float& c, float& d) {
#define STG(CT, RM) \
    a = dpp_fadd<CT,RM>(a); b = dpp_fadd<CT,RM>(b); \
    c = dpp_fadd<CT,RM>(c); d = dpp_fadd<CT,RM>(d);
    STG(0x111,0xF) STG(0x112,0xF) STG(0x114,0xF)
    STG(0x118,0xF) STG(0x142,0xA) STG(0x143,0xC)
#undef STG
    a = lane63f(a); b = lane63f(b); c = lane63f(c); d = lane63f(d);
}

__global__ __launch_bounds__(256) void dtm_kernel(
    const float* __restrict__ input,   // [B, N, 2]
    const float* __restrict__ weight,  // [B, N]
    const float* __restrict__ grid,    // [N, 2]
    float* __restrict__ out)           // [B, N]
{
    __shared__ unsigned hist[4][4 * NCOPY_STR];   // per-wave, 4 staggered copies
    const int wave = threadIdx.x >> 6;
    const int lane = threadIdx.x & 63;
    const int q    = (blockIdx.x << 2) + wave;
    const int b    = q >> 10;

    const float2 xq = reinterpret_cast<const float2*>(input)[q];

    unsigned* hrow = hist[wave];
    // zero all 260 entries (wave-private row; DS ops within a wave are ordered)
    #pragma unroll
    for (int z = 0; z < 4; ++z) hrow[lane + 64 * z] = 0u;
    if (lane < 4 * NCOPY_STR - 256) hrow[lane + 256] = 0u;

    const int base = lane * PER_LANE;
    const float4* w4 = reinterpret_cast<const float4*>(weight + (b << 10) + base);
    const float4* g4 = reinterpret_cast<const float4*>(grid + 2 * base);

    float w[PER_LANE], d2[PER_LANE];
    #pragma unroll
    for (int i = 0; i < 4; ++i) {
        const float4 x = w4[i];
        w[4*i+0] = x.x; w[4*i+1] = x.y; w[4*i+2] = x.z; w[4*i+3] = x.w;
    }

    // ---- pass0: d2 + fixed-point histogram into this lane's copy
    const int copyOff = (lane >> 4) * NCOPY_STR;
    #pragma unroll
    for (int i = 0; i < 8; ++i) {                   // 2 grid points per float4
        const float4 g = g4[i];
        #pragma unroll
        for (int j = 0; j < 2; ++j) {
            const int k  = 2*i + j;
            const float gx = j ? g.z : g.x;
            const float gy = j ? g.w : g.y;
            const float dx = xq.x - gx, dy = xq.y - gy;
            const float dk = dx * dx + dy * dy;
            d2[k] = dk;
            int ib = (int)(__float_as_uint(dk) >> 21) - (int)BUCKET_OFF;
            ib = min(max(ib, 0), 63);
            const unsigned wi = (unsigned)(w[k] * WSCALE);
            atomicAdd(&hrow[copyOff + ib], wi);     // native ds_add_u32
        }
    }

    // ---- bucket selection: merge copies, scan, ballot (round-trip 1)
    const unsigned h = hrow[lane] + hrow[NCOPY_STR + lane]
                     + hrow[2 * NCOPY_STR + lane] + hrow[3 * NCOPY_STR + lane];
    const unsigned cum  = wave_scan_u32(h);
    const unsigned totI = (unsigned)__builtin_amdgcn_readlane((int)cum, 63);
    const float    totF = (float)totI;
    const float    wb   = M0_ * totF * WINV;        // float weight bound
    const unsigned wbI  = (unsigned)(M0_ * totF);   // fixed-point bound

    const unsigned long long m = __ballot(cum >= wbI);
    const int s = (int)__ffsll(m) - 1;              // first bucket reaching wb

    const unsigned cumS = (unsigned)__builtin_amdgcn_readlane((int)cum, s);
    const unsigned hS   = (unsigned)__builtin_amdgcn_readlane((int)h,   s);

    float lo  = (s == 0) ? 0.f : __uint_as_float(((unsigned)s + BUCKET_OFF) << 21);
    float hi  = __uint_as_float(((unsigned)s + 1u + BUCKET_OFF) << 21);
    float Wlo = (s == 0) ? 0.f : (float)(cumS - hS) * WINV;
    float Whi = (float)cumS * WINV;

    // ---- 2 interpolative S-only refines (round-trips 2,3)
    #pragma unroll
    for (int it = 0; it < 2; ++it) {
        float fr = (wb - Wlo) / (Whi - Wlo);
        fr = fminf(fmaxf(fr, 0.06f), 0.94f);
        const float t = lo + (hi - lo) * fr;
        float sv = 0.f;
        #pragma unroll
        for (int k = 0; k < PER_LANE; ++k)
            sv += (d2[k] <= t) ? w[k] : 0.f;
        const float sw = wave_sum1(sv);
        if (sw >= wb) { hi = t; Whi = sw; }
        else          { lo = t; Wlo = sw; }
    }

    // ---- two-sided epilogue: strict (S,A) at lo and hi (round-trip 4)
    float Al = 0.f, Sl = 0.f, Ah = 0.f, Sh = 0.f;
    #pragma unroll
    for (int k = 0; k < PER_LANE; ++k) {
        const float dk = d2[k];
        const float wk = w[k];
        const float dw = dk * wk;
        const bool ih = (dk < hi);
        const bool il = (dk < lo);
        Ah += ih ? dw : 0.f;  Sh += ih ? wk : 0.f;
        Al += il ? dw : 0.f;  Sl += il ? wk : 0.f;
    }
    wave_sum4_u(Al, Sl, Ah, Sh);

    // concave-envelope estimate (val(t) concave piecewise-linear, max at t*;
    // tangent intersection exact when <=1 point inside the bracket)
    const float dS = Sh - Sl;
    float that = (dS > 0.f) ? (Ah - Al) / dS : hi;
    that = fminf(fmaxf(that, lo), hi);
    const float vL   = Al + that * (wb - Sl);        // tangent from lo
    const float vH   = Ah + that * (wb - Sh);        // tangent from hi
    const float vhat = fminf(vL, vH);                // upper bound on wb*val
    const float vmax = fmaxf(Al + lo * (wb - Sl),
                             Ah + hi * (wb - Sh));   // lower bound
    const float val  = 0.5f * (vhat + vmax) / wb;

    if (lane == 0) out[q] = sqrtf(fmaxf(val, 0.f));
}

extern "C" void kernel_launch(void* const* d_in, const int* in_sizes, int n_in,
                              void* d_out, int out_size, void* d_ws, size_t ws_size,
                              hipStream_t stream) {
    const float* input  = (const float*)d_in[0];   // [32,1024,2]
    const float* weight = (const float*)d_in[1];   // [32,1024]
    const float* grid   = (const float*)d_in[2];   // [1024,2]
    float* out = (float*)d_out;                    // [32,1024]

    const int total_q = 32 * 1024;                 // B*N
    dim3 blk(256);                                 // 4 waves/block, 1 query/wave
    dim3 grd(total_q / 4);                         // 8192 blocks
    hipLaunchKernelGGL(dtm_kernel, grd, blk, 0, stream,
                       input, weight, grid, out);
}

// Round 17
// 43.526 us; speedup vs baseline: 1.0312x; 1.0312x over previous
//
#include <hip/hip_runtime.h>
#include <math.h>

// DTM layer: B=32, N=1024, D=2, M0=0.05, R=2
// out = sqrt( (A_strict(t*) + t*(wb - S_strict(t*)))/wb ), t* = weighted
// 5%-quantile of d2, wb = 0.05*sum_b(w).
// R15 = R12 (best: integer LDS histogram bracketing + 2 interpolative refines
//            + two-sided concave-envelope) with instruction trims:
//  - stagger REVERTED (R14: conflicts 3.95M->3.81M, neutral-to-negative);
//  - A-ONLY epilogue: S at both bracket ends is already known exactly
//    (histogram CDF at bucket edges is strict; probe S differs from strict
//    only on measure-zero fp ties) -> only Al,Ah computed, wave_sum2 not 4.
//    NOT R13's one-sided estimate: both tangent lines of the envelope kept.
//  - bucket index clamped in raw space (med3), offset folds into addressing.

constexpr int      PER_LANE   = 16;        // 1024 / 64
constexpr float    M0_        = 0.05f;
constexpr unsigned BUCKET_LO  = 476u;      // raw = bits>>21; bucket0 at d2=2^-8
constexpr unsigned BUCKET_HI  = 539u;      // BUCKET_LO + 63
constexpr float    WSCALE     = 1048576.0f;            // 2^20
constexpr float    WINV       = 9.5367431640625e-07f;  // 2^-20

template<int CTRL, int RM>
__device__ __forceinline__ unsigned dpp_uadd(unsigned v) {
    unsigned m = (unsigned)__builtin_amdgcn_update_dpp(0, (int)v, CTRL, RM, 0xF, true);
    return v + m;
}
template<int CTRL, int RM>
__device__ __forceinline__ float dpp_fadd(float v) {
    int m = __builtin_amdgcn_update_dpp(0, __float_as_int(v), CTRL, RM, 0xF, true);
    return v + __int_as_float(m);
}
__device__ __forceinline__ float lane63f(float v) {
    return __uint_as_float((unsigned)__builtin_amdgcn_readlane(__float_as_int(v), 63));
}

// u32 inclusive prefix scan across 64 lanes
__device__ __forceinline__ unsigned wave_scan_u32(unsigned v) {
    v = dpp_uadd<0x111,0xF>(v);    // row_shr:1
    v = dpp_uadd<0x112,0xF>(v);    // row_shr:2
    v = dpp_uadd<0x114,0xF>(v);    // row_shr:4
    v = dpp_uadd<0x118,0xF>(v);    // row_shr:8
    v = dpp_uadd<0x142,0xA>(v);    // row_bcast:15
    v = dpp_uadd<0x143,0xC>(v);    // row_bcast:31
    return v;                      // lane63 = total
}
__device__ __forceinline__ float wave_sum1(float v) {
    v = dpp_fadd<0x111,0xF>(v); v = dpp_fadd<0x112,0xF>(v);
    v = dpp_fadd<0x114,0xF>(v); v = dpp_fadd<0x118,0xF>(v);
    v = dpp_fadd<0x142,0xA>(v); v = dpp_fadd<0x143,0xC>(v);
    return lane63f(v);
}
__device__ __forceinline__ void wave_sum2_u(float& a, float& b) {
    a = dpp_fadd<0x111,0xF>(a); b = dpp_fadd<0x111,0xF>(b);
    a = dpp_fadd<0x112,0xF>(a); b = dpp_fadd<0x112,0xF>(b);
    a = dpp_fadd<0x114,0xF>(a); b = dpp_fadd<0x114,0xF>(b);
    a = dpp_fadd<0x118,0xF>(a); b = dpp_fadd<0x118,0xF>(b);
    a = dpp_fadd<0x142,0xA>(a); b = dpp_fadd<0x142,0xA>(b);
    a = dpp_fadd<0x143,0xC>(a); b = dpp_fadd<0x143,0xC>(b);
    a = lane63f(a); b = lane63f(b);
}

__global__ __launch_bounds__(256) void dtm_kernel(
    const float* __restrict__ input,   // [B, N, 2]
    const float* __restrict__ weight,  // [B, N]
    const float* __restrict__ grid,    // [N, 2]
    float* __restrict__ out)           // [B, N]
{
    __shared__ unsigned hist[4][64];   // per-wave private rows -> no barriers
    const int wave = threadIdx.x >> 6;
    const int lane = threadIdx.x & 63;
    const int q    = (blockIdx.x << 2) + wave;
    const int b    = q >> 10;

    const float2 xq = reinterpret_cast<const float2*>(input)[q];

    unsigned* hrow = hist[wave];
    hrow[lane] = 0u;                   // wave-private row; DS ops wave-ordered

    const int base = lane * PER_LANE;
    const float4* w4 = reinterpret_cast<const float4*>(weight + (b << 10) + base);
    const float4* g4 = reinterpret_cast<const float4*>(grid + 2 * base);

    float w[PER_LANE], d2[PER_LANE];
    #pragma unroll
    for (int i = 0; i < 4; ++i) {
        const float4 x = w4[i];
        w[4*i+0] = x.x; w[4*i+1] = x.y; w[4*i+2] = x.z; w[4*i+3] = x.w;
    }

    // ---- pass0: d2 + fixed-point histogram (bucket = quarter-octave of d2)
    #pragma unroll
    for (int i = 0; i < 8; ++i) {                   // 2 grid points per float4
        const float4 g = g4[i];
        #pragma unroll
        for (int j = 0; j < 2; ++j) {
            const int k  = 2*i + j;
            const float gx = j ? g.z : g.x;
            const float gy = j ? g.w : g.y;
            const float dx = xq.x - gx, dy = xq.y - gy;
            const float dk = dx * dx + dy * dy;
            d2[k] = dk;
            // clamp in raw-index space: med3, offset folds into addressing
            const unsigned raw = __float_as_uint(dk) >> 21;
            const unsigned ibr = min(max(raw, BUCKET_LO), BUCKET_HI);
            const unsigned wi  = (unsigned)(w[k] * WSCALE);
            atomicAdd(&hrow[ibr - BUCKET_LO], wi);  // native ds_add_u32
        }
    }

    // ---- bucket selection: scan + ballot (round-trip 1)
    const unsigned h    = hrow[lane];               // wave-private, no barrier
    const unsigned cum  = wave_scan_u32(h);
    const unsigned totI = (unsigned)__builtin_amdgcn_readlane((int)cum, 63);
    const float    totF = (float)totI;
    const float    wb   = M0_ * totF * WINV;        // float weight bound
    const unsigned wbI  = (unsigned)(M0_ * totF);   // fixed-point bound

    const unsigned long long m = __ballot(cum >= wbI);
    const int s = (int)__ffsll(m) - 1;              // first bucket reaching wb

    const unsigned cumS = (unsigned)__builtin_amdgcn_readlane((int)cum, s);
    const unsigned hS   = (unsigned)__builtin_amdgcn_readlane((int)h,   s);

    // bucket edges; histogram CDF at an edge IS the strict sum there
    float lo  = (s == 0) ? 0.f : __uint_as_float(((unsigned)s + BUCKET_LO) << 21);
    float hi  = __uint_as_float(((unsigned)s + 1u + BUCKET_LO) << 21);
    float Wlo = (s == 0) ? 0.f : (float)(cumS - hS) * WINV;
    float Whi = (float)cumS * WINV;

    // ---- 2 interpolative S-only refines (round-trips 2,3)
    #pragma unroll
    for (int it = 0; it < 2; ++it) {
        float fr = (wb - Wlo) / (Whi - Wlo);
        fr = fminf(fmaxf(fr, 0.06f), 0.94f);
        const float t = lo + (hi - lo) * fr;
        float sv = 0.f;
        #pragma unroll
        for (int k = 0; k < PER_LANE; ++k)
            sv += (d2[k] <= t) ? w[k] : 0.f;
        const float sw = wave_sum1(sv);
        if (sw >= wb) { hi = t; Whi = sw; }
        else          { lo = t; Wlo = sw; }
    }

    // ---- A-only epilogue: strict A at lo and hi (round-trip 4).
    // S at both ends = Wlo/Whi (strict at edges; probes differ from strict
    // only on exact fp ties -> measure zero).
    float Al = 0.f, Ah = 0.f;
    #pragma unroll
    for (int k = 0; k < PER_LANE; ++k) {
        const float dk = d2[k];
        const float dw = dk * w[k];
        Ah += (dk < hi) ? dw : 0.f;
        Al += (dk < lo) ? dw : 0.f;
    }
    wave_sum2_u(Al, Ah);

    // concave-envelope estimate (val(t) concave piecewise-linear, max at t*;
    // tangent intersection exact when <=1 point inside the bracket)
    const float dS = Whi - Wlo;                      // > 0 (Whi >= wb > Wlo)
    float that = (Ah - Al) / dS;
    that = fminf(fmaxf(that, lo), hi);
    const float vL   = Al + that * (wb - Wlo);       // tangent from lo
    const float vH   = Ah + that * (wb - Whi);       // tangent from hi
    const float vhat = fminf(vL, vH);                // upper bound on wb*val
    const float vmax = fmaxf(Al + lo * (wb - Wlo),
                             Ah + hi * (wb - Whi));  // lower bound
    const float val  = 0.5f * (vhat + vmax) / wb;

    if (lane == 0) out[q] = sqrtf(fmaxf(val, 0.f));
}

extern "C" void kernel_launch(void* const* d_in, const int* in_sizes, int n_in,
                              void* d_out, int out_size, void* d_ws, size_t ws_size,
                              hipStream_t stream) {
    const float* input  = (const float*)d_in[0];   // [32,1024,2]
    const float* weight = (const float*)d_in[1];   // [32,1024]
    const float* grid   = (const float*)d_in[2];   // [1024,2]
    float* out = (float*)d_out;                    // [32,1024]

    const int total_q = 32 * 1024;                 // B*N
    dim3 blk(256);                                 // 4 waves/block, 1 query/wave
    dim3 grd(total_q / 4);                         // 8192 blocks
    hipLaunchKernelGGL(dtm_kernel, grd, blk, 0, stream,
                       input, weight, grid, out);
}